// Round 7
// baseline (171.986 us; speedup 1.0000x reference)
//
#include <hip/hip_runtime.h>
#include <math.h>

#define N_NODES 1024
#define N_EVAL 131072
#define NUM_POLES 8
#define PI_D 3.14159265358979323846

// ws layout: float4 pk[1024] = (node, w, w*v, 0) per node.
//
// Closed-form barycentric weights for Chebyshev points of the 2nd kind
// x_j = cos(pi*j/n), n = N_NODES-1:
//   1/prod_{i!=j}(x_j-x_i) = (-1)^j * delta_j * 2^(n-1)/n, delta=1/2 at ends.
// Uniform positive scalings (2^(n-1)/n, exp(-max), /|w[0]|) cancel in
// num/den, so: w_j = (-1)^j * delta_j * prod_m((x_j-pr_m)^2 + pi_m^2).
__global__ void wk_setup(const float* __restrict__ values,
                         const float* __restrict__ poles_real,
                         const float* __restrict__ poles_imag,
                         float4* __restrict__ pk) {
    const int j = blockIdx.x * 128 + threadIdx.x;
    const double nd = cos(PI_D * (double)j / (double)(N_NODES - 1));
    double prod = (j == 0 || j == N_NODES - 1) ? 0.5 : 1.0;
#pragma unroll
    for (int m = 0; m < NUM_POLES; ++m) {
        const double dr = nd - (double)poles_real[m];
        const double di = (double)poles_imag[m];
        prod *= dr * dr + di * di;
    }
    if (j & 1) prod = -prod;
    pk[j] = make_float4((float)nd, (float)prod,
                        (float)(prod * (double)values[j]), 0.0f);
}

// Eval: block = 4 waves, 128 points/block. Wave layout: wid = 2*pointgroup +
// half; wave (pg,h) sums node half h (512 nodes) for points pg*64+lane.
// The node stream is wave-uniform: laundered uniform pointer + uniform loop
// index lets the COMPILER emit s_load (scalar pipe) with its own pipelined
// lgkmcnt(N) waits — no LDS, no vector loads, no inline asm in the hot loop
// (R5's failure was the hand-forced lgkmcnt(0) barrier per iteration).
// Per node: v_sub(v,s,v) + v_rcp + 2x v_fmac(v,s,v) = 3 VALU + 1 trans,
// each reading at most 1 SGPR (ISA-legal). Plain rcp, no Newton (~1 ulp,
// validated R2/R3). Exact node hits (d==0) poison accumulators with inf/NaN
// -> rare global-scan fix-up (reference: exact-hit column reduces to
// sum(hit wv)/sum(hit w)).
__global__ __launch_bounds__(256, 4) void eval_kernel(
    const float* __restrict__ x_eval,
    const float4* __restrict__ pk,
    float* __restrict__ out) {
    const int t = threadIdx.x;
    const int lane = t & 63;
    const int wid  = t >> 6;     // 0..3
    const int half = wid & 1;    // node half
    const int pg   = wid >> 1;   // point group
    const int pbase = blockIdx.x * 128;
    const float x = x_eval[pbase + pg * 64 + lane];

    // Wave-uniform node-table pointer, laundered into SGPRs.
    unsigned long long up = (unsigned long long)(pk + half * (N_NODES / 2));
    const unsigned lo = __builtin_amdgcn_readfirstlane((unsigned)up);
    const unsigned hi = __builtin_amdgcn_readfirstlane((unsigned)(up >> 32));
    const float4* tp = (const float4*)((((unsigned long long)hi) << 32) | lo);

    float n0 = 0.0f, d0 = 0.0f, n1 = 0.0f, d1 = 0.0f;

#pragma unroll 4
    for (int j = 0; j < N_NODES / 2; j += 2) {
        const float4 e0 = tp[j];
        const float4 e1 = tp[j + 1];
        const float da = x - e0.x;
        const float db = x - e1.x;
        const float ra = __builtin_amdgcn_rcpf(da);
        const float rb = __builtin_amdgcn_rcpf(db);
        n0 = fmaf(e0.z, ra, n0);
        d0 = fmaf(e0.y, ra, d0);
        n1 = fmaf(e1.z, rb, n1);
        d1 = fmaf(e1.y, rb, d1);
    }

    __shared__ float2 s_r[4][64];
    s_r[wid][lane] = make_float2(n0 + n1, d0 + d1);
    __syncthreads();

    if (wid < 2) {
        const float2 a = s_r[wid * 2][lane];
        const float2 b = s_r[wid * 2 + 1][lane];
        const float nn = a.x + b.x;
        const float dd = a.y + b.y;
        float res = nn / dd;
        const int p = pbase + wid * 64 + lane;
        if (__builtin_expect(__builtin_isnan(res), 0)) {
            const float xx = x_eval[p];
            float hn = 0.0f, hd = 0.0f;
            for (int jj = 0; jj < N_NODES; ++jj) {
                const float4 e = pk[jj];
                if (e.x == xx) { hn += e.z; hd += e.y; }
            }
            res = hn / hd;
        }
        out[p] = res;
    }
}

extern "C" void kernel_launch(void* const* d_in, const int* in_sizes, int n_in,
                              void* d_out, int out_size, void* d_ws, size_t ws_size,
                              hipStream_t stream) {
    const float* x_eval     = (const float*)d_in[0];
    const float* values     = (const float*)d_in[1];
    const float* poles_real = (const float*)d_in[2];
    const float* poles_imag = (const float*)d_in[3];
    float* out = (float*)d_out;

    float4* pk = (float4*)d_ws;

    wk_setup<<<8, 128, 0, stream>>>(values, poles_real, poles_imag, pk);
    eval_kernel<<<N_EVAL / 128, 256, 0, stream>>>(x_eval, pk, out);
}

// Round 8
// 138.306 us; speedup vs baseline: 1.2435x; 1.2435x over previous
//
#include <hip/hip_runtime.h>
#include <math.h>

#define N_NODES 1024
#define N_EVAL 131072
#define NUM_POLES 8
#define PI_D 3.14159265358979323846

// Single fused kernel. Block = 512 threads = 8 waves; 128 points/block
// (2 per lane); wave w covers node chunk [128w, 128w+128) for all 128
// block-points. Grid 1024 blocks = 4 blocks/CU = 32 waves/CU = 8 waves/SIMD
// (max occupancy — R1..R7 all ran <=4 waves/SIMD and were latency-exposed).
//
// LDS budget: per CU, ds_read_b128 instrs = 0.75 * 8192 / P; P=2 pts/thread
// halves R1's 31 us LDS wall to ~15 us while keeping grid large.
//
// Phase 1: closed-form barycentric weights (redundant per block, cheap).
// Chebyshev points 2nd kind x_j = cos(pi*j/n), n = N_NODES-1:
//   1/prod_{i!=j}(x_j-x_i) = (-1)^j * delta_j * 2^(n-1)/n, delta=1/2 at ends.
// Uniform positive scalings (2^(n-1)/n, exp(-max), /|w[0]|) cancel in
// num/den: w_j = (-1)^j * delta_j * prod_m((x_j-pr_m)^2 + pi_m^2).
//
// Phase 2: hot loop, branchless: per node 2 sub + 2 rcp + 4 fma (two points
// -> 4 independent FMA chains). unroll 4 -> 12 b128 broadcast loads in
// flight per iteration (R1's best trait). Exact hits (d==0) poison the
// accumulators with inf/NaN (validated R2/R3).
//
// Phase 3: 8-way LDS reduction, divide, rare NaN fix-up
// (reference: exact-hit column reduces to sum(hit wv)/sum(hit w)).
__global__ __launch_bounds__(512, 8) void eval_kernel(
    const float* __restrict__ x_eval,
    const float* __restrict__ values,
    const float* __restrict__ poles_real,
    const float* __restrict__ poles_imag,
    float* __restrict__ out) {
    __shared__ __align__(16) float s_n[N_NODES];
    __shared__ __align__(16) float s_w[N_NODES];
    __shared__ __align__(16) float s_v[N_NODES];
    __shared__ float2 s_r[8][128];

    const int t = threadIdx.x;

    // ---- Phase 1: weights -> LDS ----
#pragma unroll
    for (int h = 0; h < 2; ++h) {
        const int j = t + h * 512;
        const double nd = cos(PI_D * (double)j / (double)(N_NODES - 1));
        double prod = (j == 0 || j == N_NODES - 1) ? 0.5 : 1.0;
#pragma unroll
        for (int m = 0; m < NUM_POLES; ++m) {
            const double dr = nd - (double)poles_real[m];
            const double di = (double)poles_imag[m];
            prod *= dr * dr + di * di;
        }
        if (j & 1) prod = -prod;
        s_n[j] = (float)nd;
        s_w[j] = (float)prod;
        s_v[j] = (float)(prod * (double)values[j]);
    }
    __syncthreads();

    // ---- Phase 2: wave = 128-node chunk, 2 points/thread ----
    const int lane = t & 63;
    const int wid  = t >> 6;  // 0..7
    const int pbase = blockIdx.x * 128;
    const float x0 = x_eval[pbase + lane];
    const float x1 = x_eval[pbase + 64 + lane];

    const float4* n4 = (const float4*)s_n + wid * 32;
    const float4* w4 = (const float4*)s_w + wid * 32;
    const float4* v4 = (const float4*)s_v + wid * 32;

    float a0 = 0.0f, b0 = 0.0f;  // num/den for x0
    float a1 = 0.0f, b1 = 0.0f;  // num/den for x1

#define NODE(C)                                                            \
    {                                                                      \
        const float d0 = x0 - an.C;                                        \
        const float d1 = x1 - an.C;                                        \
        const float r0 = __builtin_amdgcn_rcpf(d0);                        \
        const float r1 = __builtin_amdgcn_rcpf(d1);                        \
        a0 = fmaf(av.C, r0, a0); b0 = fmaf(aw.C, r0, b0);                  \
        a1 = fmaf(av.C, r1, a1); b1 = fmaf(aw.C, r1, b1);                  \
    }

#pragma unroll 4
    for (int q = 0; q < 32; ++q) {
        const float4 an = n4[q];
        const float4 aw = w4[q];
        const float4 av = v4[q];
        NODE(x) NODE(y) NODE(z) NODE(w)
    }
#undef NODE

    s_r[wid][lane]      = make_float2(a0, b0);
    s_r[wid][lane + 64] = make_float2(a1, b1);
    __syncthreads();

    // ---- Phase 3: reduce 8 wave-partials, divide, fix exact hits ----
    if (t < 128) {
        float nn = 0.0f, dd = 0.0f;
#pragma unroll
        for (int w = 0; w < 8; ++w) {
            const float2 pr = s_r[w][t];
            nn += pr.x;
            dd += pr.y;
        }
        float res = nn / dd;
        if (__builtin_expect(__builtin_isnan(res), 0)) {
            const float x = x_eval[pbase + t];
            float hn = 0.0f, hd = 0.0f;
            for (int j = 0; j < N_NODES; ++j) {
                if (s_n[j] == x) { hn += s_v[j]; hd += s_w[j]; }
            }
            res = hn / hd;
        }
        out[pbase + t] = res;
    }
}

extern "C" void kernel_launch(void* const* d_in, const int* in_sizes, int n_in,
                              void* d_out, int out_size, void* d_ws, size_t ws_size,
                              hipStream_t stream) {
    const float* x_eval     = (const float*)d_in[0];
    const float* values     = (const float*)d_in[1];
    const float* poles_real = (const float*)d_in[2];
    const float* poles_imag = (const float*)d_in[3];
    float* out = (float*)d_out;

    eval_kernel<<<N_EVAL / 128, 512, 0, stream>>>(x_eval, values,
                                                  poles_real, poles_imag, out);
}

// Round 9
// 126.828 us; speedup vs baseline: 1.3561x; 1.0905x over previous
//
#include <hip/hip_runtime.h>
#include <math.h>

#define N_NODES 1024
#define N_EVAL 131072
#define NUM_POLES 8
#define PI_D 3.14159265358979323846

// Single fused kernel, R6 structure + explicit register prefetch.
// Block = 512 threads = 8 waves; 256 points/block (4 per lane); wave w
// covers node chunk [128w,128w+128) for all 256 block-points. Grid 512
// blocks = 2 blocks/CU = 16 waves/CU. launch_bounds(512,4): VGPR cap 128 —
// R8's (512,8) cap of 64 caused 40 MB of scratch spill (FETCH/WRITE blowup).
//
// Hot loop: software-pipelined — group q+1's three float4s are loaded into
// registers BEFORE computing group q, so the compiler's lgkmcnt wait sits
// ~224 issue-cycles after the ds_read (vs ~0 in R6) and the ~120-cyc LDS
// latency is hidden per-wave, not per-occupancy.
//
// Phase 1: closed-form barycentric weights (redundant per block, f64).
// Chebyshev 2nd-kind x_j = cos(pi*j/n): 1/prod_{i!=j}(x_j-x_i) =
// (-1)^j*delta_j*2^(n-1)/n, delta=1/2 at ends; uniform positive scalings
// cancel in num/den -> w_j = (-1)^j*delta_j*prod_m((x_j-pr_m)^2+pi_m^2).
//
// Exact node hits (d==0) poison accumulators with inf/NaN -> rare fix-up
// (reference: exact-hit column reduces to sum(hit wv)/sum(hit w)).
__global__ __launch_bounds__(512, 4) void eval_kernel(
    const float* __restrict__ x_eval,
    const float* __restrict__ values,
    const float* __restrict__ poles_real,
    const float* __restrict__ poles_imag,
    float* __restrict__ out) {
    __shared__ __align__(16) float s_n[N_NODES];
    __shared__ __align__(16) float s_w[N_NODES];
    __shared__ __align__(16) float s_v[N_NODES];
    __shared__ float2 s_r[8][256];

    const int t = threadIdx.x;

    // ---- Phase 1: weights -> LDS ----
#pragma unroll
    for (int h = 0; h < 2; ++h) {
        const int j = t + h * 512;
        const double nd = cos(PI_D * (double)j / (double)(N_NODES - 1));
        double prod = (j == 0 || j == N_NODES - 1) ? 0.5 : 1.0;
#pragma unroll
        for (int m = 0; m < NUM_POLES; ++m) {
            const double dr = nd - (double)poles_real[m];
            const double di = (double)poles_imag[m];
            prod *= dr * dr + di * di;
        }
        if (j & 1) prod = -prod;
        s_n[j] = (float)nd;
        s_w[j] = (float)prod;
        s_v[j] = (float)(prod * (double)values[j]);
    }
    __syncthreads();

    // ---- Phase 2: wave = 128-node chunk, 4 points/thread, prefetched ----
    const int lane = t & 63;
    const int wid  = t >> 6;  // 0..7
    const int pbase = blockIdx.x * 256;
    const float x0 = x_eval[pbase + lane];
    const float x1 = x_eval[pbase + 64 + lane];
    const float x2 = x_eval[pbase + 128 + lane];
    const float x3 = x_eval[pbase + 192 + lane];

    const float4* n4 = (const float4*)s_n + wid * 32;
    const float4* w4 = (const float4*)s_w + wid * 32;
    const float4* v4 = (const float4*)s_v + wid * 32;

    float a0 = 0.0f, b0 = 0.0f, a1 = 0.0f, b1 = 0.0f;
    float a2 = 0.0f, b2 = 0.0f, a3 = 0.0f, b3 = 0.0f;

#define NODE(C)                                                            \
    {                                                                      \
        const float d0 = x0 - an.C;                                        \
        const float d1 = x1 - an.C;                                        \
        const float d2 = x2 - an.C;                                        \
        const float d3 = x3 - an.C;                                        \
        const float r0 = __builtin_amdgcn_rcpf(d0);                        \
        const float r1 = __builtin_amdgcn_rcpf(d1);                        \
        const float r2 = __builtin_amdgcn_rcpf(d2);                        \
        const float r3 = __builtin_amdgcn_rcpf(d3);                        \
        a0 = fmaf(av.C, r0, a0); b0 = fmaf(aw.C, r0, b0);                  \
        a1 = fmaf(av.C, r1, a1); b1 = fmaf(aw.C, r1, b1);                  \
        a2 = fmaf(av.C, r2, a2); b2 = fmaf(aw.C, r2, b2);                  \
        a3 = fmaf(av.C, r3, a3); b3 = fmaf(aw.C, r3, b3);                  \
    }

    float4 an = n4[0];
    float4 aw = w4[0];
    float4 av = v4[0];
#pragma unroll 1
    for (int q = 0; q < 31; ++q) {
        // Prefetch next group before consuming the current one.
        const float4 pn = n4[q + 1];
        const float4 pw = w4[q + 1];
        const float4 pv = v4[q + 1];
        NODE(x) NODE(y) NODE(z) NODE(w)
        an = pn; aw = pw; av = pv;
    }
    NODE(x) NODE(y) NODE(z) NODE(w)  // peeled last group
#undef NODE

    s_r[wid][lane]       = make_float2(a0, b0);
    s_r[wid][lane + 64]  = make_float2(a1, b1);
    s_r[wid][lane + 128] = make_float2(a2, b2);
    s_r[wid][lane + 192] = make_float2(a3, b3);
    __syncthreads();

    // ---- Phase 3: reduce 8 wave-partials, divide, fix exact hits ----
    if (t < 256) {
        float nn = 0.0f, dd = 0.0f;
#pragma unroll
        for (int w = 0; w < 8; ++w) {
            const float2 pr = s_r[w][t];
            nn += pr.x;
            dd += pr.y;
        }
        float res = nn / dd;
        if (__builtin_expect(__builtin_isnan(res), 0)) {
            const float x = x_eval[pbase + t];
            float hn = 0.0f, hd = 0.0f;
            for (int j = 0; j < N_NODES; ++j) {
                if (s_n[j] == x) { hn += s_v[j]; hd += s_w[j]; }
            }
            res = hn / hd;
        }
        out[pbase + t] = res;
    }
}

extern "C" void kernel_launch(void* const* d_in, const int* in_sizes, int n_in,
                              void* d_out, int out_size, void* d_ws, size_t ws_size,
                              hipStream_t stream) {
    const float* x_eval     = (const float*)d_in[0];
    const float* values     = (const float*)d_in[1];
    const float* poles_real = (const float*)d_in[2];
    const float* poles_imag = (const float*)d_in[3];
    float* out = (float*)d_out;

    eval_kernel<<<N_EVAL / 256, 512, 0, stream>>>(x_eval, values,
                                                  poles_real, poles_imag, out);
}